// Round 7
// baseline (112.104 us; speedup 1.0000x reference)
//
#include <hip/hip_runtime.h>

#define NUM_NODES 10000
#define NUM_EDGES 640000
#define D_FEAT 128

// Buckets of 16 nodes: 10000/16 = 625 exactly.
#define BSHIFT 4
#define NPB 16                       // nodes per bucket
#define NB 625                       // buckets
#define BLOCKS 256                   // scatter partition blocks
#define EPB (NUM_EDGES / BLOCKS)     // 2500 edges per block
// Per-(bucket,block) cell: count ~ Poisson(2500*16/10000 = 4).
// CELL_CAP=16 words = 64 B = exactly ONE cache line: single-writer per line
// (XCD-safe plain stores). P(cell > 16 | lam=4) ~ 4e-7; x160K cells -> ~0.06
// expected overflows, which go to a global overflow list patched in by K2.
// LESSON (R4): global atomicAdd binning = 195us (VALUBusy 0.2%) -- contended
// device-scope RMW serializes ~190ns/op per address. Never again.
//
// R7 = MEASUREMENT ROUND: the entire pipeline is launched TWICE.
// dur7 - dur6 = (K1 + K2) exactly, resolving whether the residual ~41us
// above the 43.5us poison fill is kernel time or harness floor.
#define CELL_CAP 16
#define MAXB 1344                    // per-bucket total bound (mean 1024, +10sd)
#define OVF_CAP 1024

// x in bf16: one row = 128 bf16 = 256 B = 16 uint4.
#define XB_U4 (NUM_NODES * 16)           // 160000 uint4
#define CVT_PER_BLOCK (XB_U4 / BLOCKS)   // 625 uint4 per block

// ---------------------------------------------------------------------------
// Workspace (d_ws):
//   xb      [XB_U4]             uint4 -- x in bf16 (2.56 MB, L2/L3-resident)
//   cnt     [BLOCKS*NB]         u32   -- cnt[b*NB+k] words in cell (0.64 MB)
//   slots   [NB*BLOCKS*CELL_CAP]u32   -- cell (k,b) at (k*256+b)*16 (10.24 MB)
//   ovf_cnt [16]                u32   -- global overflow counter (memset 0)
//   ovf     [OVF_CAP]           u32   -- overflow entries k<<18|m<<14|src
// Total ~13.5 MB.
// ---------------------------------------------------------------------------

__device__ __forceinline__ unsigned bf16_rne(float f) {
    unsigned u = __float_as_uint(f);
    return (u + 0x7FFFu + ((u >> 16) & 1u)) >> 16;
}

// K1: fused f32->bf16 conversion + scatter into private one-line cells.
__global__ __launch_bounds__(1024) void scatter_cvt_kernel(
    const int* __restrict__ ei, const float4* __restrict__ x4,
    uint4* __restrict__ xb, unsigned* __restrict__ cnt,
    unsigned* __restrict__ slots, unsigned* __restrict__ ovf_cnt,
    unsigned* __restrict__ ovf)
{
    __shared__ int cur[NB];
    int t = threadIdx.x, b = blockIdx.x;
    if (t < NB) cur[t] = 0;

    // hoisted edge loads: EPB=2500 over 1024 threads = 2 full rounds + tail
    int base = b * EPB;
    int s0 = ei[base + t];
    int d0 = ei[NUM_EDGES + base + t];
    int s1 = ei[base + t + 1024];          // t+1024 <= 2047 < 2500: valid
    int d1 = ei[NUM_EDGES + base + t + 1024];
    int s2 = 0, d2 = 0;
    bool has2 = (t + 2048) < EPB;          // t < 452
    if (has2) {
        s2 = ei[base + t + 2048];
        d2 = ei[NUM_EDGES + base + t + 2048];
    }

    // fused conversion: 625 uint4 (= 5000 floats) per block, single round
    if (t < CVT_PER_BLOCK) {
        int o = b * CVT_PER_BLOCK + t;
        float4 a = x4[2 * o];
        float4 c = x4[2 * o + 1];
        uint4 w;
        w.x = bf16_rne(a.x) | (bf16_rne(a.y) << 16);
        w.y = bf16_rne(a.z) | (bf16_rne(a.w) << 16);
        w.z = bf16_rne(c.x) | (bf16_rne(c.y) << 16);
        w.w = bf16_rne(c.z) | (bf16_rne(c.w) << 16);
        xb[o] = w;
    }
    __syncthreads();   // cur[] zeroed before atomics

    {
        int k = d0 >> BSHIFT;
        int pos = atomicAdd(&cur[k], 1);
        if (pos < CELL_CAP)
            slots[(unsigned)(k * BLOCKS + b) * CELL_CAP + (unsigned)pos] =
                ((unsigned)(d0 & (NPB - 1)) << 16) | (unsigned)s0;
        else {
            unsigned g = atomicAdd(ovf_cnt, 1u);
            if (g < OVF_CAP)
                ovf[g] = ((unsigned)k << 18) |
                         ((unsigned)(d0 & (NPB - 1)) << 14) | (unsigned)s0;
        }
    }
    {
        int k = d1 >> BSHIFT;
        int pos = atomicAdd(&cur[k], 1);
        if (pos < CELL_CAP)
            slots[(unsigned)(k * BLOCKS + b) * CELL_CAP + (unsigned)pos] =
                ((unsigned)(d1 & (NPB - 1)) << 16) | (unsigned)s1;
        else {
            unsigned g = atomicAdd(ovf_cnt, 1u);
            if (g < OVF_CAP)
                ovf[g] = ((unsigned)k << 18) |
                         ((unsigned)(d1 & (NPB - 1)) << 14) | (unsigned)s1;
        }
    }
    if (has2) {
        int k = d2 >> BSHIFT;
        int pos = atomicAdd(&cur[k], 1);
        if (pos < CELL_CAP)
            slots[(unsigned)(k * BLOCKS + b) * CELL_CAP + (unsigned)pos] =
                ((unsigned)(d2 & (NPB - 1)) << 16) | (unsigned)s2;
        else {
            unsigned g = atomicAdd(ovf_cnt, 1u);
            if (g < OVF_CAP)
                ovf[g] = ((unsigned)k << 18) |
                         ((unsigned)(d2 & (NPB - 1)) << 14) | (unsigned)s2;
        }
    }
    __syncthreads();
    // coalesced per-block count row (block-private lines: XCD-safe)
    if (t < NB) cnt[b * NB + t] = (unsigned)min(cur[t], CELL_CAP);
}

__device__ __forceinline__ void acc8(float* a, uint4 w) {
    a[0] += __uint_as_float(w.x << 16);
    a[1] += __uint_as_float(w.x & 0xFFFF0000u);
    a[2] += __uint_as_float(w.y << 16);
    a[3] += __uint_as_float(w.y & 0xFFFF0000u);
    a[4] += __uint_as_float(w.z << 16);
    a[5] += __uint_as_float(w.z & 0xFFFF0000u);
    a[6] += __uint_as_float(w.w << 16);
    a[7] += __uint_as_float(w.w & 0xFFFF0000u);
}

// K2: per-bucket node-sort + bf16 gather (unchanged from R6).
__global__ __launch_bounds__(1024) void sort_gather_kernel(
    const uint4* __restrict__ xb,            // [NUM_NODES * 16] bf16 rows
    const unsigned* __restrict__ cnt,        // [BLOCKS*NB]
    const uint4* __restrict__ slots4,        // cells as uint4 (4 per cell)
    const unsigned* __restrict__ ovf_cnt,
    const unsigned* __restrict__ ovf,
    float4* __restrict__ out4)               // [NUM_NODES * 32]
{
    __shared__ int s_cnt[BLOCKS];
    __shared__ unsigned s_src[MAXB];
    __shared__ int h[NPB];
    __shared__ int off16[NPB];
    __shared__ int cur16[NPB];

    int k = blockIdx.x;
    int t = threadIdx.x;

    if (t < NPB) h[t] = 0;
    if (t < BLOCKS) s_cnt[t] = (int)cnt[t * NB + k];   // strided, L3-absorbed
    __syncthreads();

    // this bucket's 256 cells as 1024 uint4 (coalesced): uint4 idx t covers
    // cell c = t>>2, quarter su = t&3.
    const uint4* sb = slots4 + (unsigned)k * BLOCKS * (CELL_CAP / 4);
    uint4 w4 = sb[t];
    int v = s_cnt[t >> 2] - (t & 3) * 4;
    int vc = max(0, min(4, v));
    if (vc > 0) atomicAdd(&h[w4.x >> 16], 1);
    if (vc > 1) atomicAdd(&h[w4.y >> 16], 1);
    if (vc > 2) atomicAdd(&h[w4.z >> 16], 1);
    if (vc > 3) atomicAdd(&h[w4.w >> 16], 1);
    // overflow contributions (almost always none)
    int no = (int)min(*ovf_cnt, (unsigned)OVF_CAP);
    for (int i = t; i < no; i += 1024) {
        unsigned e = ovf[i];
        if ((int)(e >> 18) == k) atomicAdd(&h[(e >> 14) & 15u], 1);
    }
    __syncthreads();

    // 16-lane shfl prefix scan (wave 0)
    if (t < NPB) {
        int vv = h[t];
        int s = vv;
        #pragma unroll
        for (int d = 1; d < 16; d <<= 1) {
            int u = __shfl_up(s, d, 16);
            if (t >= d) s += u;
        }
        off16[t] = s - vv;
        cur16[t] = s - vv;
    }
    __syncthreads();

    // compact into s_src grouped by node
    if (vc > 0) { int p = atomicAdd(&cur16[w4.x >> 16], 1); if (p < MAXB) s_src[p] = w4.x & 0xFFFFu; }
    if (vc > 1) { int p = atomicAdd(&cur16[w4.y >> 16], 1); if (p < MAXB) s_src[p] = w4.y & 0xFFFFu; }
    if (vc > 2) { int p = atomicAdd(&cur16[w4.z >> 16], 1); if (p < MAXB) s_src[p] = w4.z & 0xFFFFu; }
    if (vc > 3) { int p = atomicAdd(&cur16[w4.w >> 16], 1); if (p < MAXB) s_src[p] = w4.w & 0xFFFFu; }
    for (int i = t; i < no; i += 1024) {
        unsigned e = ovf[i];
        if ((int)(e >> 18) == k) {
            int p = atomicAdd(&cur16[(e >> 14) & 15u], 1);
            if (p < MAXB) s_src[p] = e & 0x3FFFu;
        }
    }
    __syncthreads();

    int m    = t >> 6;          // wave -> node within bucket (0..15)
    int lane = t & 63;
    int q    = lane >> 4;       // which edge of the quad
    int sub  = lane & 15;       // 16 B chunk (8 bf16) within the row

    int beg  = off16[m], ec = h[m];
    int last = ec > 0 ? ec - 1 : 0;

    float a[8] = {0.f, 0.f, 0.f, 0.f, 0.f, 0.f, 0.f, 0.f};

    // depth-2 pipeline: group j in regs while j+4 prefetches
    bool val = q < ec;
    unsigned i0 = (unsigned)min(beg + min(q, last), MAXB - 1);
    uint4 wv = xb[(s_src[i0] & 0xFFFFu) * 16u + (unsigned)sub];

    for (int j = 0; j < ec; j += 4) {
        int jn = j + 4;
        unsigned i1 = (unsigned)min(beg + min(jn + q, last), MAXB - 1);
        uint4 wv1 = xb[(s_src[i1] & 0xFFFFu) * 16u + (unsigned)sub];
        bool val1 = (jn + q) < ec;
        if (val) acc8(a, wv);
        wv = wv1; val = val1;
    }

    #pragma unroll
    for (int r = 0; r < 8; ++r) {
        a[r] += __shfl_down(a[r], 32);
        a[r] += __shfl_down(a[r], 16);
    }
    if (q == 0) {
        unsigned o = (unsigned)(k * NPB + m) * 32u + (unsigned)sub * 2u;
        out4[o]     = make_float4(a[0], a[1], a[2], a[3]);
        out4[o + 1] = make_float4(a[4], a[5], a[6], a[7]);
    }
}

extern "C" void kernel_launch(void* const* d_in, const int* in_sizes, int n_in,
                              void* d_out, int out_size, void* d_ws, size_t ws_size,
                              hipStream_t stream) {
    const float* x   = (const float*)d_in[0];   // [10000, 128] f32
    const int*   ei  = (const int*)d_in[1];     // [2, 640000] int32
    float*       out = (float*)d_out;           // [10000, 128] f32

    uint4*    xb      = (uint4*)d_ws;                              // 2.56 MB
    unsigned* cnt     = (unsigned*)(xb + XB_U4);                   // 0.64 MB
    unsigned* slots   = cnt + BLOCKS * NB;                         // 10.24 MB
    unsigned* ovf_cnt = slots + (size_t)NB * BLOCKS * CELL_CAP;    // 64 B
    unsigned* ovf     = ovf_cnt + 16;                              // 4 KB

    // ---- pass 1 (identical to R6) ----
    hipMemsetAsync(ovf_cnt, 0, sizeof(unsigned), stream);
    scatter_cvt_kernel<<<BLOCKS, 1024, 0, stream>>>(
        ei, (const float4*)x, xb, cnt, slots, ovf_cnt, ovf);
    sort_gather_kernel<<<NB, 1024, 0, stream>>>(
        xb, cnt, (const uint4*)slots, ovf_cnt, ovf, (float4*)out);

    // ---- pass 2: MEASUREMENT duplicate. Idempotent re-run; ovf_cnt reset
    // so a (p~6e-2) overflow can't double-log. dur_R7 - dur_R6 = K1 + K2.
    hipMemsetAsync(ovf_cnt, 0, sizeof(unsigned), stream);
    scatter_cvt_kernel<<<BLOCKS, 1024, 0, stream>>>(
        ei, (const float4*)x, xb, cnt, slots, ovf_cnt, ovf);
    sort_gather_kernel<<<NB, 1024, 0, stream>>>(
        xb, cnt, (const uint4*)slots, ovf_cnt, ovf, (float4*)out);
}

// Round 8
// 81.240 us; speedup vs baseline: 1.3799x; 1.3799x over previous
//
#include <hip/hip_runtime.h>

#define NUM_NODES 10000
#define NUM_EDGES 640000
#define D_FEAT 128

// Buckets of 20 nodes: 10000/20 = 500 exactly. 500 K2 blocks all co-resident
// (2 blocks/CU x 256 CUs = 512 >= 500) -> one scheduling round, max 2
// buckets/CU vs mean 1.95 (2.5% tail; the 625-bucket layout had 23%).
#define NPB 20
#define NB 500
#define K1_BLOCKS 256
#define EPB (NUM_EDGES / K1_BLOCKS)      // 2500 edges per block
// Cell (k,b): count ~ Poisson(2500*20/10000 = 5). CELL_CAP=16 words = 64 B =
// one line, block-private (XCD-safe). P(cell>16|lam=5) ~ 1.4e-5 -> ~2
// expected overflows total; they go to the per-block ovfcell line (below).
// LESSON (R4): global atomic binning = 195us. LESSON (R7 measurement):
// K1+K2 = 27.4us of dur=85; harness floor ~57us.
#define CELL_CAP 16
#define MAXB 1664                        // bucket total: mean 1280 + 10 sigma
// Poison-proof overflow: cnt[b][k] stores the UNCAPPED cursor; cnt>16 tells
// K2 to scan ovfcell[b] (16 dwords, sentinel 0xFFFFFFFF-padded, written
// every launch from LDS) filtering entries by k. No global counter, no
// memset dispatch, all lines block-private.

// x in bf16: one row = 128 bf16 = 256 B = 16 uint4.
#define XB_U4 (NUM_NODES * 16)           // 160000 uint4
#define CVT_PER_BLOCK (XB_U4 / K1_BLOCKS) // 625 uint4 per block

// ---------------------------------------------------------------------------
// Workspace (d_ws):
//   xb      [XB_U4]                uint4 -- x in bf16 (2.56 MB)
//   cnt     [K1_BLOCKS*NB]         u32   -- uncapped cursors (0.512 MB)
//   ovfcell [K1_BLOCKS*16]         u32   -- per-block overflow line (16 KB)
//   slots   [NB*K1_BLOCKS*CELL_CAP]u32   -- cell (k,b) at (k*256+b)*16 (8.19 MB)
// Total ~11.3 MB. No memset needed.
// ---------------------------------------------------------------------------

__device__ __forceinline__ unsigned bf16_rne(float f) {
    unsigned u = __float_as_uint(f);
    return (u + 0x7FFFu + ((u >> 16) & 1u)) >> 16;
}

__device__ __forceinline__ int bucket_of(int d) {
    // exact floor(d/20) for 0 <= d < 262144 (Granlund-Montgomery, e=8)
    return (int)(((unsigned)d * 104858u) >> 21);
}

// K1: fused f32->bf16 conversion + scatter into LDS cells, then COALESCED
// full-line cell write-out (fixes R4's 37 MB scattered-dword write storm).
__global__ __launch_bounds__(1024) void scatter_cvt_kernel(
    const int* __restrict__ ei, const float4* __restrict__ x4,
    uint4* __restrict__ xb, unsigned* __restrict__ cnt,
    unsigned* __restrict__ ovfcell, uint4* __restrict__ slots4)
{
    __shared__ int cur[NB];
    __shared__ uint4 cellsv[NB * (CELL_CAP / 4)];   // 32 KB: [k][16 words]
    __shared__ unsigned s_ovf[16];
    __shared__ int ovfcur;

    int t = threadIdx.x, b = blockIdx.x;
    if (t < NB) cur[t] = 0;
    if (t < 16) s_ovf[t] = 0xFFFFFFFFu;             // sentinel: k-field 8191
    if (t == 0) ovfcur = 0;

    // hoisted edge loads: 2500 over 1024 threads = 2 rounds + tail
    int base = b * EPB;
    int s0 = ei[base + t];
    int d0 = ei[NUM_EDGES + base + t];
    int s1 = ei[base + t + 1024];                   // t+1024 <= 2047 < 2500
    int d1 = ei[NUM_EDGES + base + t + 1024];
    int s2 = 0, d2 = 0;
    bool has2 = (t + 2048) < EPB;                   // t < 452
    if (has2) {
        s2 = ei[base + t + 2048];
        d2 = ei[NUM_EDGES + base + t + 2048];
    }

    // fused conversion: 625 uint4 (= 5000 floats) per block
    if (t < CVT_PER_BLOCK) {
        int o = b * CVT_PER_BLOCK + t;
        float4 a = x4[2 * o];
        float4 c = x4[2 * o + 1];
        uint4 w;
        w.x = bf16_rne(a.x) | (bf16_rne(a.y) << 16);
        w.y = bf16_rne(a.z) | (bf16_rne(a.w) << 16);
        w.z = bf16_rne(c.x) | (bf16_rne(c.y) << 16);
        w.w = bf16_rne(c.z) | (bf16_rne(c.w) << 16);
        xb[o] = w;
    }
    __syncthreads();    // cur/s_ovf init done

    unsigned* cells = (unsigned*)cellsv;
    {
        int k = bucket_of(d0), m = d0 - k * NPB;
        int pos = atomicAdd(&cur[k], 1);
        if (pos < CELL_CAP)
            cells[k * CELL_CAP + pos] = ((unsigned)m << 16) | (unsigned)s0;
        else {
            int o = atomicAdd(&ovfcur, 1);
            if (o < 16) s_ovf[o] = ((unsigned)k << 19) |
                                   ((unsigned)m << 14) | (unsigned)s0;
        }
    }
    {
        int k = bucket_of(d1), m = d1 - k * NPB;
        int pos = atomicAdd(&cur[k], 1);
        if (pos < CELL_CAP)
            cells[k * CELL_CAP + pos] = ((unsigned)m << 16) | (unsigned)s1;
        else {
            int o = atomicAdd(&ovfcur, 1);
            if (o < 16) s_ovf[o] = ((unsigned)k << 19) |
                                   ((unsigned)m << 14) | (unsigned)s1;
        }
    }
    if (has2) {
        int k = bucket_of(d2), m = d2 - k * NPB;
        int pos = atomicAdd(&cur[k], 1);
        if (pos < CELL_CAP)
            cells[k * CELL_CAP + pos] = ((unsigned)m << 16) | (unsigned)s2;
        else {
            int o = atomicAdd(&ovfcur, 1);
            if (o < 16) s_ovf[o] = ((unsigned)k << 19) |
                                   ((unsigned)m << 14) | (unsigned)s2;
        }
    }
    __syncthreads();

    // coalesced cell write-out: 4 consecutive lanes emit one full 64 B line.
    // 2000 uint4 over 1024 threads = 2 ragged rounds.
    for (int idx = t; idx < NB * (CELL_CAP / 4); idx += 1024) {
        int k = idx >> 2, j = idx & 3;
        slots4[((unsigned)k * K1_BLOCKS + (unsigned)b) * (CELL_CAP / 4) + j] =
            cellsv[idx];
    }
    // uncapped cursor row (block-private lines) + sentinel-padded ovf line
    if (t < NB) cnt[b * NB + t] = (unsigned)cur[t];
    if (t < 16) ovfcell[b * 16 + t] = s_ovf[t];
}

__device__ __forceinline__ void acc8(float* a, uint4 w) {
    a[0] += __uint_as_float(w.x << 16);
    a[1] += __uint_as_float(w.x & 0xFFFF0000u);
    a[2] += __uint_as_float(w.y << 16);
    a[3] += __uint_as_float(w.y & 0xFFFF0000u);
    a[4] += __uint_as_float(w.z << 16);
    a[5] += __uint_as_float(w.z & 0xFFFF0000u);
    a[6] += __uint_as_float(w.w << 16);
    a[7] += __uint_as_float(w.w & 0xFFFF0000u);
}

// K2: 500 blocks x 640 threads (10 waves). Wave w handles nodes 2w, 2w+1
// sequentially (balanced sum of two Poissons, no max() straggler).
// __launch_bounds__(640,5): VGPR<=96 -> 2 blocks/CU -> all 500 co-resident.
__global__ __launch_bounds__(640, 5) void sort_gather_kernel(
    const uint4* __restrict__ xb,            // [NUM_NODES*16] bf16 rows
    const unsigned* __restrict__ cnt,        // [K1_BLOCKS*NB] uncapped
    const uint4* __restrict__ slots4,        // cells, 4 uint4 each
    const unsigned* __restrict__ ovfcell,    // [K1_BLOCKS*16]
    float4* __restrict__ out4)               // [NUM_NODES*32]
{
    __shared__ int s_cnt[K1_BLOCKS];
    __shared__ unsigned s_src[MAXB];
    __shared__ int h[NPB];
    __shared__ int off20[NPB];
    __shared__ int cur20[NPB];

    int k = blockIdx.x;
    int t = threadIdx.x;

    if (t < NPB) h[t] = 0;
    if (t < K1_BLOCKS) s_cnt[t] = (int)cnt[t * NB + k];   // strided, L2-hot
    __syncthreads();

    // bucket's 256 cells = 1024 uint4, read in 2 coalesced rounds
    const uint4* sb = slots4 + (unsigned)k * (K1_BLOCKS * CELL_CAP / 4);
    uint4 w40, w41 = make_uint4(0u, 0u, 0u, 0u);
    int vc0, vc1 = 0;
    {
        int c = t >> 2, su = t & 3;
        w40 = sb[t];
        int v = min(s_cnt[c], CELL_CAP) - su * 4;
        vc0 = max(0, min(4, v));
    }
    if (t < 384) {                                        // t+640 < 1024
        int idx = t + 640;
        int c = idx >> 2, su = idx & 3;
        w41 = sb[idx];
        int v = min(s_cnt[c], CELL_CAP) - su * 4;
        vc1 = max(0, min(4, v));
    }
    if (vc0 > 0) atomicAdd(&h[w40.x >> 16], 1);
    if (vc0 > 1) atomicAdd(&h[w40.y >> 16], 1);
    if (vc0 > 2) atomicAdd(&h[w40.z >> 16], 1);
    if (vc0 > 3) atomicAdd(&h[w40.w >> 16], 1);
    if (vc1 > 0) atomicAdd(&h[w41.x >> 16], 1);
    if (vc1 > 1) atomicAdd(&h[w41.y >> 16], 1);
    if (vc1 > 2) atomicAdd(&h[w41.z >> 16], 1);
    if (vc1 > 3) atomicAdd(&h[w41.w >> 16], 1);
    // rare overflow path: cnt>CAP flags block t's ovfcell line
    if (t < K1_BLOCKS && s_cnt[t] > CELL_CAP) {
        for (int i = 0; i < 16; ++i) {
            unsigned e = ovfcell[t * 16 + i];
            if ((int)(e >> 19) == k) atomicAdd(&h[(e >> 14) & 31u], 1);
        }
    }
    __syncthreads();

    // 32-lane shfl prefix scan over 20 counters (wave 0)
    if (t < 32) {
        int val = (t < NPB) ? h[t] : 0;
        int s = val;
        #pragma unroll
        for (int d = 1; d < 32; d <<= 1) {
            int u = __shfl_up(s, d, 32);
            if (t >= d) s += u;
        }
        if (t < NPB) { off20[t] = s - val; cur20[t] = s - val; }
    }
    __syncthreads();

    // compact into s_src grouped by node
    if (vc0 > 0) { int p = atomicAdd(&cur20[w40.x >> 16], 1); if (p < MAXB) s_src[p] = w40.x & 0xFFFFu; }
    if (vc0 > 1) { int p = atomicAdd(&cur20[w40.y >> 16], 1); if (p < MAXB) s_src[p] = w40.y & 0xFFFFu; }
    if (vc0 > 2) { int p = atomicAdd(&cur20[w40.z >> 16], 1); if (p < MAXB) s_src[p] = w40.z & 0xFFFFu; }
    if (vc0 > 3) { int p = atomicAdd(&cur20[w40.w >> 16], 1); if (p < MAXB) s_src[p] = w40.w & 0xFFFFu; }
    if (vc1 > 0) { int p = atomicAdd(&cur20[w41.x >> 16], 1); if (p < MAXB) s_src[p] = w41.x & 0xFFFFu; }
    if (vc1 > 1) { int p = atomicAdd(&cur20[w41.y >> 16], 1); if (p < MAXB) s_src[p] = w41.y & 0xFFFFu; }
    if (vc1 > 2) { int p = atomicAdd(&cur20[w41.z >> 16], 1); if (p < MAXB) s_src[p] = w41.z & 0xFFFFu; }
    if (vc1 > 3) { int p = atomicAdd(&cur20[w41.w >> 16], 1); if (p < MAXB) s_src[p] = w41.w & 0xFFFFu; }
    if (t < K1_BLOCKS && s_cnt[t] > CELL_CAP) {
        for (int i = 0; i < 16; ++i) {
            unsigned e = ovfcell[t * 16 + i];
            if ((int)(e >> 19) == k) {
                int p = atomicAdd(&cur20[(e >> 14) & 31u], 1);
                if (p < MAXB) s_src[p] = e & 0x3FFFu;
            }
        }
    }
    __syncthreads();

    int wave = t >> 6;          // 0..9
    int lane = t & 63;
    int q    = lane >> 4;       // which edge of the quad
    int sub  = lane & 15;       // 16 B chunk (8 bf16) within the row

    #pragma unroll
    for (int mm = 0; mm < 2; ++mm) {
        int m = wave * 2 + mm;
        int beg = off20[m], ec = h[m];
        int last = ec > 0 ? ec - 1 : 0;

        float a[8] = {0.f, 0.f, 0.f, 0.f, 0.f, 0.f, 0.f, 0.f};

        // depth-2 pipeline: group j in regs while j+4 prefetches (clamped
        // indices memory-safe; invalid quads masked from accumulate)
        bool val = q < ec;
        unsigned i0 = (unsigned)min(beg + min(q, last), MAXB - 1);
        uint4 wv = xb[(s_src[i0] & 0xFFFFu) * 16u + (unsigned)sub];

        for (int j = 0; j < ec; j += 4) {
            int jn = j + 4;
            unsigned i1 = (unsigned)min(beg + min(jn + q, last), MAXB - 1);
            uint4 wv1 = xb[(s_src[i1] & 0xFFFFu) * 16u + (unsigned)sub];
            bool val1 = (jn + q) < ec;
            if (val) acc8(a, wv);
            wv = wv1; val = val1;
        }

        #pragma unroll
        for (int r = 0; r < 8; ++r) {
            a[r] += __shfl_down(a[r], 32);
            a[r] += __shfl_down(a[r], 16);
        }
        if (q == 0) {
            unsigned o = (unsigned)(k * NPB + m) * 32u + (unsigned)sub * 2u;
            out4[o]     = make_float4(a[0], a[1], a[2], a[3]);
            out4[o + 1] = make_float4(a[4], a[5], a[6], a[7]);
        }
    }
}

extern "C" void kernel_launch(void* const* d_in, const int* in_sizes, int n_in,
                              void* d_out, int out_size, void* d_ws, size_t ws_size,
                              hipStream_t stream) {
    const float* x   = (const float*)d_in[0];   // [10000, 128] f32
    const int*   ei  = (const int*)d_in[1];     // [2, 640000] int32
    float*       out = (float*)d_out;           // [10000, 128] f32

    uint4*    xb      = (uint4*)d_ws;                        // 2.56 MB
    unsigned* cnt     = (unsigned*)(xb + XB_U4);             // 0.512 MB
    unsigned* ovfcell = cnt + K1_BLOCKS * NB;                // 16 KB
    uint4*    slots4  = (uint4*)(ovfcell + K1_BLOCKS * 16);  // 8.19 MB

    // K1: convert x -> bf16 + LDS-cell scatter + coalesced cell write-out
    scatter_cvt_kernel<<<K1_BLOCKS, 1024, 0, stream>>>(
        ei, (const float4*)x, xb, cnt, ovfcell, slots4);

    // K2: per-bucket histogram/scan/compact + bf16 gather (one round, 500 blk)
    sort_gather_kernel<<<NB, 640, 0, stream>>>(
        xb, cnt, (const uint4*)slots4, ovfcell, (float4*)out);
}